// Round 1
// baseline (138.098 us; speedup 1.0000x reference)
//
#include <hip/hip_runtime.h>

// OccupancyGridForestAS: per-point voxel lookup in a forest of 64 dense 64^3 grids,
// addressed via an 8^3 block->tree lookup table.
//
// Inputs (setup_inputs order):
//   d_in[0]: pts            float32 [4194304, 3]
//   d_in[1]: occ_val_grid   float32 [64, 64, 64, 64]
//   d_in[2]: block_lookup   int32   [8, 8, 8]
// Output: float32 [4194304]
//
// Memory-bound gather kernel. 4 points per thread: 3x float4 coalesced loads
// for the xyz stream, 4 independent random gathers (ILP to hide HBM latency),
// 1x float4 coalesced store.

#define LDIM 8
#define RES  64

__global__ __launch_bounds__(256) void occ_forest_kernel(
    const float4* __restrict__ pts4,
    const float*  __restrict__ grid,
    const int*    __restrict__ lookup,
    float4*       __restrict__ out4,
    int n4)
{
    int j = blockIdx.x * blockDim.x + threadIdx.x;
    if (j >= n4) return;

    // 4 points = 12 floats = 3 float4s, fully coalesced.
    float4 a = pts4[3 * j + 0];
    float4 b = pts4[3 * j + 1];
    float4 c = pts4[3 * j + 2];

    float px[4] = {a.x, a.w, b.z, c.y};
    float py[4] = {a.y, b.x, b.w, c.z};
    float pz[4] = {a.z, b.y, c.x, c.w};

    float r[4];
#pragma unroll
    for (int k = 0; k < 4; ++k) {
        float x = px[k], y = py[k], z = pz[k];

        // bc = floor(pts); in_dom = all in [0, L)
        float fx = floorf(x), fy = floorf(y), fz = floorf(z);
        int bx = (int)fx, by = (int)fy, bz = (int)fz;
        bool in_dom = (bx >= 0) & (bx < LDIM) &
                      (by >= 0) & (by < LDIM) &
                      (bz >= 0) & (bz < LDIM);
        int cx = min(max(bx, 0), LDIM - 1);
        int cy = min(max(by, 0), LDIM - 1);
        int cz = min(max(bz, 0), LDIM - 1);

        int bidx = lookup[(cx * LDIM + cy) * LDIM + cz];
        if (!in_dom) bidx = -1;

        // Reference float op sequence, replicated exactly:
        // block_x = 2*(p - bcs) - 1 ; t = (block_x*0.5 + 0.5)*res ; vox = clip(floor(t),0,res-1)
        float bxf = 2.0f * (x - (float)cx) - 1.0f;
        float byf = 2.0f * (y - (float)cy) - 1.0f;
        float bzf = 2.0f * (z - (float)cz) - 1.0f;
        float tx = (bxf * 0.5f + 0.5f) * (float)RES;
        float ty = (byf * 0.5f + 0.5f) * (float)RES;
        float tz = (bzf * 0.5f + 0.5f) * (float)RES;
        int vx = min(max((int)floorf(tx), 0), RES - 1);
        int vy = min(max((int)floorf(ty), 0), RES - 1);
        int vz = min(max((int)floorf(tz), 0), RES - 1);

        float val = 0.0f;
        if (bidx >= 0) {
            int idx = ((bidx * RES + vx) * RES + vy) * RES + vz;  // < 2^24, fits int
            val = grid[idx];
        }
        r[k] = val;
    }

    out4[j] = make_float4(r[0], r[1], r[2], r[3]);
}

extern "C" void kernel_launch(void* const* d_in, const int* in_sizes, int n_in,
                              void* d_out, int out_size, void* d_ws, size_t ws_size,
                              hipStream_t stream) {
    const float* pts    = (const float*)d_in[0];
    const float* grid   = (const float*)d_in[1];
    const int*   lookup = (const int*)d_in[2];
    float*       out    = (float*)d_out;

    // out_size = 4194304, divisible by 4; 4 points per thread.
    int n4 = out_size / 4;
    int threads = 256;
    int blocks = (n4 + threads - 1) / threads;
    occ_forest_kernel<<<blocks, threads, 0, stream>>>(
        (const float4*)pts, grid, lookup, (float4*)out, n4);
}